// Round 6
// baseline (989.720 us; speedup 1.0000x reference)
//
#include <hip/hip_runtime.h>

#define N_NODES 100000
#define N_EDGES 1600000
#define FEAT 64
#define BUCKET_SHIFT 7                 // 128 nodes per bucket
#define NODES_PER_BUCKET (1 << BUCKET_SHIFT)
#define NBUCK ((N_NODES + NODES_PER_BUCKET - 1) / NODES_PER_BUCKET)  // 782

// ---------------- CSR build ----------------

__global__ void count_deg_kernel(const int* __restrict__ dst, int* __restrict__ deg,
                                 int n_edges) {
    int i = blockIdx.x * blockDim.x + threadIdx.x;
    int stride = gridDim.x * blockDim.x;
    for (; i < n_edges; i += stride) {
        atomicAdd(&deg[dst[i]], 1);
    }
}

// per-block sums of deg (256 elems per block)
__global__ void scan_block_sums(const int* __restrict__ deg, int* __restrict__ bsum, int n) {
    __shared__ int sdata[256];
    int t = threadIdx.x;
    int i = blockIdx.x * 256 + t;
    sdata[t] = (i < n) ? deg[i] : 0;
    __syncthreads();
    for (int s = 128; s > 0; s >>= 1) {
        if (t < s) sdata[t] += sdata[t + s];
        __syncthreads();
    }
    if (t == 0) bsum[blockIdx.x] = sdata[0];
}

// exclusive scan of block sums (single block, nb <= 512)
__global__ void scan_partials(const int* __restrict__ bsum, int* __restrict__ bpref, int nb) {
    __shared__ int sdata[512];
    int t = threadIdx.x;
    int v = (t < nb) ? bsum[t] : 0;
    sdata[t] = v;
    __syncthreads();
    for (int off = 1; off < 512; off <<= 1) {
        int add = (t >= off) ? sdata[t - off] : 0;
        __syncthreads();
        sdata[t] += add;
        __syncthreads();
    }
    if (t < nb) bpref[t] = sdata[t] - v;  // exclusive prefix
}

// per-block exclusive scan + add block prefix -> row_start, cursor
__global__ void scan_final(const int* __restrict__ deg, const int* __restrict__ bpref,
                           int* __restrict__ row_start, int* __restrict__ cursor, int n) {
    __shared__ int sdata[256];
    int t = threadIdx.x;
    int i = blockIdx.x * 256 + t;
    int v = (i < n) ? deg[i] : 0;
    sdata[t] = v;
    __syncthreads();
    for (int off = 1; off < 256; off <<= 1) {
        int add = (t >= off) ? sdata[t - off] : 0;
        __syncthreads();
        sdata[t] += add;
        __syncthreads();
    }
    int incl = sdata[t];
    int excl = incl - v;
    int base = bpref[blockIdx.x];
    if (i < n) {
        row_start[i] = base + excl;
        cursor[i]    = base + excl;
        if (i == n - 1) row_start[n] = base + incl;  // total = N_EDGES
    }
}

// bucket cursors start at the CSR offset of each bucket's first node
__global__ void init_bucket_cursors(const int* __restrict__ row_start,
                                    int* __restrict__ bucket_cursor) {
    int b = blockIdx.x * blockDim.x + threadIdx.x;
    if (b < NBUCK) {
        int node = b << BUCKET_SHIFT;
        if (node > N_NODES) node = N_NODES;
        bucket_cursor[b] = row_start[node];
    }
}

// Pass A: append (src,dst) pairs into per-bucket dense regions.
// Appends within a bucket land adjacent -> full cache-line utilization.
__global__ void bin_edges(const int* __restrict__ src, const int* __restrict__ dst,
                          int* __restrict__ bucket_cursor, int2* __restrict__ pairs,
                          int n_edges) {
    int i = blockIdx.x * blockDim.x + threadIdx.x;
    int stride = gridDim.x * blockDim.x;
    for (; i < n_edges; i += stride) {
        int s = src[i];
        int d = dst[i];
        int slot = atomicAdd(&bucket_cursor[d >> BUCKET_SHIFT], 1);
        pairs[slot] = make_int2(s, d);
    }
}

// Pass B: one block per bucket; finalize CSR placement. Each bucket's
// src_sorted range (~8 KB) is dense and L2-resident -> full lines written.
__global__ void place_edges(const int2* __restrict__ pairs, const int* __restrict__ row_start,
                            int* __restrict__ cursor, int* __restrict__ src_sorted,
                            int n_nodes) {
    int b = blockIdx.x;
    int n0 = b << BUCKET_SHIFT;
    int n1 = n0 + NODES_PER_BUCKET;
    if (n0 > n_nodes) n0 = n_nodes;
    if (n1 > n_nodes) n1 = n_nodes;
    int beg = row_start[n0];
    int end = row_start[n1];
    for (int e = beg + threadIdx.x; e < end; e += blockDim.x) {
        int2 p = pairs[e];
        int slot = atomicAdd(&cursor[p.y], 1);
        src_sorted[slot] = p.x;
    }
}

// ---------------- fused GIN layer ----------------
// One wave per node. Lane map: g = lane>>4 (edge slot), c = lane&15 (float4
// feature chunk). One issued load covers 4 edge-rows (4x MLP vs lane=feature);
// unroll x2 -> 8 edges in flight. Cross-group combine via 8 shfl_xor. Then
// 64x64 matmul via readlane(chunk lane c, component) broadcast with W row
// held per-lane (lane j = output feature j). Optional ReLU.
template <int OUTF, bool RELU>
__global__ __launch_bounds__(256) void gin_layer(
    const float* __restrict__ in, const int* __restrict__ row_start,
    const int* __restrict__ src_sorted, const float* __restrict__ W,
    const float* __restrict__ bias, float* __restrict__ out, int n_nodes) {
    const int lane = threadIdx.x & 63;
    const int g = lane >> 4;   // row group 0..3
    const int c = lane & 15;   // float4 chunk 0..15
    int wid = (int)((blockIdx.x * blockDim.x + threadIdx.x) >> 6);
    const int nw = (int)((gridDim.x * blockDim.x) >> 6);
    wid = __builtin_amdgcn_readfirstlane(wid);  // wave-uniform -> SGPR

    const float4* inv = (const float4*)in;  // row stride 16 float4

    // lane j computes output feature j: needs W[j][k] for k=0..63
    const int jc = (OUTF == 64) ? lane : ((lane < OUTF) ? lane : 0);
    float Wc[64];
#pragma unroll
    for (int k = 0; k < 64; ++k) Wc[k] = W[jc * 64 + k];
    const float bj = bias[jc];

    for (int node = wid; node < n_nodes; node += nw) {
        const int e0 = row_start[node];
        const int e1 = row_start[node + 1];

        // self term: group 0 only (other groups start at zero)
        float4 a0 = make_float4(0.f, 0.f, 0.f, 0.f);
        float4 a1 = make_float4(0.f, 0.f, 0.f, 0.f);
        if (g == 0) a0 = inv[(size_t)node * 16 + c];

        for (int e = e0; e < e1; e += 8) {
            int i0 = e + g;
            int i1 = e + g + 4;
            if (i0 < e1) {
                int s = src_sorted[i0];
                float4 v = inv[(size_t)s * 16 + c];
                a0.x += v.x; a0.y += v.y; a0.z += v.z; a0.w += v.w;
            }
            if (i1 < e1) {
                int s = src_sorted[i1];
                float4 v = inv[(size_t)s * 16 + c];
                a1.x += v.x; a1.y += v.y; a1.z += v.z; a1.w += v.w;
            }
        }
        a0.x += a1.x; a0.y += a1.y; a0.z += a1.z; a0.w += a1.w;

        // combine across the 4 row-groups (lanes differing in bits 4,5)
        a0.x += __shfl_xor(a0.x, 16); a0.y += __shfl_xor(a0.y, 16);
        a0.z += __shfl_xor(a0.z, 16); a0.w += __shfl_xor(a0.w, 16);
        a0.x += __shfl_xor(a0.x, 32); a0.y += __shfl_xor(a0.y, 32);
        a0.z += __shfl_xor(a0.z, 32); a0.w += __shfl_xor(a0.w, 32);
        // now lane with chunk cc holds feats [4cc..4cc+3] of the aggregated row

        // out[j] = b[j] + sum_k row[k] * W[j][k]; row[4cc+i] from lane cc
        float acc = bj;
#pragma unroll
        for (int cc = 0; cc < 16; ++cc) {
            float vx = __int_as_float(__builtin_amdgcn_readlane(__float_as_int(a0.x), cc));
            float vy = __int_as_float(__builtin_amdgcn_readlane(__float_as_int(a0.y), cc));
            float vz = __int_as_float(__builtin_amdgcn_readlane(__float_as_int(a0.z), cc));
            float vw = __int_as_float(__builtin_amdgcn_readlane(__float_as_int(a0.w), cc));
            acc = fmaf(vx, Wc[4 * cc + 0], acc);
            acc = fmaf(vy, Wc[4 * cc + 1], acc);
            acc = fmaf(vz, Wc[4 * cc + 2], acc);
            acc = fmaf(vw, Wc[4 * cc + 3], acc);
        }
        if (OUTF == 64 || lane < OUTF) {
            out[(size_t)node * OUTF + lane] = RELU ? fmaxf(acc, 0.0f) : acc;
        }
    }
}

// ---------------- launcher ----------------

extern "C" void kernel_launch(void* const* d_in, const int* in_sizes, int n_in,
                              void* d_out, int out_size, void* d_ws, size_t ws_size,
                              hipStream_t stream) {
    const float* x  = (const float*)d_in[0];
    const int*   ei = (const int*)d_in[1];
    const int*   src = ei;
    const int*   dst = ei + N_EDGES;
    const float* W1 = (const float*)d_in[2];
    const float* b1 = (const float*)d_in[3];
    const float* W2 = (const float*)d_in[4];
    const float* b2 = (const float*)d_in[5];
    const float* W3 = (const float*)d_in[6];
    const float* b3 = (const float*)d_in[7];
    const float* W4 = (const float*)d_in[8];
    const float* b4 = (const float*)d_in[9];
    float* out = (float*)d_out;

    // workspace layout (256B aligned)
    char* ws = (char*)d_ws;
    size_t off = 0;
    auto carve = [&](size_t bytes) {
        char* p = ws + off;
        off += (bytes + 255) & ~(size_t)255;
        return p;
    };
    int* deg           = (int*)carve(N_NODES * sizeof(int));
    int* cursor        = (int*)carve(N_NODES * sizeof(int));
    int* row_start     = (int*)carve((N_NODES + 1) * sizeof(int));
    int* bsum          = (int*)carve(512 * sizeof(int));
    int* bpref         = (int*)carve(512 * sizeof(int));
    int* bucket_cursor = (int*)carve(NBUCK * sizeof(int));
    int* src_sorted    = (int*)carve((size_t)N_EDGES * sizeof(int));
    float* h1          = (float*)carve((size_t)N_NODES * FEAT * sizeof(float));
    float* h2          = (float*)carve((size_t)N_NODES * FEAT * sizeof(float));
    // pairs buffer aliases h2: pairs is dead before layer 2 writes h2
    int2* pairs        = (int2*)h2;
    (void)ws_size;

    const int NB = (N_NODES + 255) / 256;  // 391

    hipMemsetAsync(deg, 0, N_NODES * sizeof(int), stream);
    count_deg_kernel<<<2048, 256, 0, stream>>>(dst, deg, N_EDGES);
    scan_block_sums<<<NB, 256, 0, stream>>>(deg, bsum, N_NODES);
    scan_partials<<<1, 512, 0, stream>>>(bsum, bpref, NB);
    scan_final<<<NB, 256, 0, stream>>>(deg, bpref, row_start, cursor, N_NODES);
    init_bucket_cursors<<<(NBUCK + 255) / 256, 256, 0, stream>>>(row_start, bucket_cursor);
    bin_edges<<<2048, 256, 0, stream>>>(src, dst, bucket_cursor, pairs, N_EDGES);
    place_edges<<<NBUCK, 256, 0, stream>>>(pairs, row_start, cursor, src_sorted, N_NODES);

    gin_layer<64, true><<<2048, 256, 0, stream>>>(x,  row_start, src_sorted, W1, b1, h1, N_NODES);
    gin_layer<64, true><<<2048, 256, 0, stream>>>(h1, row_start, src_sorted, W2, b2, h2, N_NODES);
    gin_layer<64, true><<<2048, 256, 0, stream>>>(h2, row_start, src_sorted, W3, b3, h1, N_NODES);
    gin_layer<10, false><<<2048, 256, 0, stream>>>(h1, row_start, src_sorted, W4, b4, out, N_NODES);
}